// Round 10
// baseline (86.480 us; speedup 1.0000x reference)
//
#include <hip/hip_runtime.h>
#include <hip/hip_bf16.h>

#define KK 32
#define DD 512
#define BB 16
#define NN 4096

typedef __attribute__((ext_vector_type(8))) short short8;
typedef __attribute__((ext_vector_type(4))) float f32x4;

__device__ __forceinline__ unsigned short f2bf(float f) {
    unsigned u = __builtin_bit_cast(unsigned, f);
    u += 0x7fffu + ((u >> 16) & 1u);   // RNE bf16
    return (unsigned short)(u >> 16);
}
// packed bf16 pair (RNE): low = a, high = b
__device__ __forceinline__ unsigned pk2(float a, float b) {
    return (unsigned)f2bf(a) | ((unsigned)f2bf(b) << 16);
}

// ---------------- kernel 0: c2[k], s2[k], codes -> permuted MFMA-frag layout ----------------
// codesP[it][kt] is a 1KB region: lane(g*16+c) holds codes[kt*16+c][it*32+g*8 .. +7] bf16.
__global__ __launch_bounds__(256) void k_prep(const float* __restrict__ codes,
                                              const float* __restrict__ scale,
                                              float* __restrict__ c2w,
                                              float* __restrict__ s2w,
                                              unsigned short* __restrict__ codesP) {
    __shared__ float red[KK][8];
    int tid = threadIdx.x;
    int k = tid >> 3, pt = tid & 7;
    int kt = k >> 4, cc = k & 15;
    const float4* p = reinterpret_cast<const float4*>(codes + k * DD + pt * 64);
    float s = 0.f;
#pragma unroll
    for (int i = 0; i < 16; ++i) {
        float4 v = p[i];
        s += v.x * v.x + v.y * v.y + v.z * v.z + v.w * v.w;
        int d0 = pt * 64 + i * 4;
        int it = d0 >> 5, g = (d0 >> 3) & 3;
        uint2 pk = make_uint2(pk2(v.x, v.y), pk2(v.z, v.w));
        ushort4 h = __builtin_bit_cast(ushort4, pk);
        int idx = ((it * 2 + kt) << 9) + (g * 16 + cc) * 8 + (d0 & 7);
        *reinterpret_cast<ushort4*>(codesP + idx) = h;
    }
    red[k][pt] = s;
    __syncthreads();
    if (tid < KK) {
        float c2 = 0.f;
#pragma unroll
        for (int j = 0; j < 8; ++j) c2 += red[tid][j];
        c2w[tid] = c2;
        float sc = scale[tid];
        s2w[tid] = sc * sc;
    }
}

// ---------------- pass A: softmax assignments (deep-pipelined staging) ----------------
// 256 thr (4 waves), 64 tokens/block, grid = 1024. 8 windows of 64 d-rows.
// Hot-loop barriers wait lgkmcnt only -> global prefetches stay in flight across barriers.
__global__ __launch_bounds__(256) void k_assign(const float* __restrict__ x,
                                                const unsigned short* __restrict__ codesP,
                                                const float* __restrict__ c2w,
                                                const float* __restrict__ s2w,
                                                unsigned short* __restrict__ Aout,
                                                float* __restrict__ sAp) {
    __shared__ unsigned short xt[2][64 * 64];   // 2 x 8 KB, swizzled [d64][tok64]
    __shared__ float x2_lds[16][64];
    __shared__ float x2f[64];
    __shared__ float sA_lds[4][32];

    int tid = threadIdx.x;
    int lane = tid & 63;
    int w = tid >> 6;          // wave -> 16 tokens
    int g = lane >> 4, c = lane & 15;
    int bid = blockIdx.x;
    int b = bid >> 6;
    int chunk = bid & 63;
    int tok_base = chunk << 6;

    int srow = tid >> 4;       // 0..15 ; rows srow*4 + i (i 0..3) per window
    int q = tid & 15;          // float4 token-column
    const float* xb = x + (size_t)b * DD * NN + tok_base + q * 4;

    float s2k0 = s2w[c], s2k1 = s2w[c + 16];
    float c2k0 = c2w[c], c2k1 = c2w[c + 16];

    f32x4 acc0 = {}, acc1 = {};
    float x2p[4] = {0.f, 0.f, 0.f, 0.f};
    float4 ld[2][4];

    auto issue = [&](int win, int slot) {
#pragma unroll
        for (int i = 0; i < 4; ++i)
            ld[slot][i] = *reinterpret_cast<const float4*>(
                xb + (size_t)(win * 64 + srow * 4 + i) * NN);
    };
    auto write_tile = [&](int buf, int slot) {
        char* bp = reinterpret_cast<char*>(&xt[buf][0]);
#pragma unroll
        for (int i = 0; i < 4; ++i) {
            float4 v = ld[slot][i];
            x2p[0] += v.x * v.x;
            x2p[1] += v.y * v.y;
            x2p[2] += v.z * v.z;
            x2p[3] += v.w * v.w;
            uint2 pk = make_uint2(pk2(v.x, v.y), pk2(v.z, v.w));
            ushort4 h = __builtin_bit_cast(ushort4, pk);
            int rl = srow * 4 + i;
            int byte = ((rl << 7) + (q << 3)) ^ (((rl >> 3) & 3) << 5);
            *reinterpret_cast<ushort4*>(bp + byte) = h;
        }
    };

    issue(0, 0);
    issue(1, 1);
    write_tile(0, 0);
    asm volatile("s_waitcnt lgkmcnt(0)" ::: "memory");
    __builtin_amdgcn_s_barrier();
    __builtin_amdgcn_sched_barrier(0);

#pragma unroll
    for (int win = 0; win < 8; ++win) {
        if (win <= 5) issue(win + 2, win & 1);
        const char* bp = reinterpret_cast<const char*>(&xt[win & 1][0]);
#pragma unroll
        for (int ksl = 0; ksl < 2; ++ksl) {
            int ks = win * 2 + ksl;
            short8 af;
#pragma unroll
            for (int j = 0; j < 8; ++j) {
                int rl = ksl * 32 + g * 8 + j;
                af[j] = *reinterpret_cast<const short*>(
                    bp + ((((rl << 7) + ((w * 16 + c) << 1)) ^ ((g & 3) << 5))));
            }
            // coalesced permuted codes frags (L2-hot): 16B per lane, wave-linear
            short8 b0 = *reinterpret_cast<const short8*>(codesP + ((ks * 2 + 0) << 9) + lane * 8);
            short8 b1 = *reinterpret_cast<const short8*>(codesP + ((ks * 2 + 1) << 9) + lane * 8);
            acc0 = __builtin_amdgcn_mfma_f32_16x16x32_bf16(af, b0, acc0, 0, 0, 0);
            acc1 = __builtin_amdgcn_mfma_f32_16x16x32_bf16(af, b1, acc1, 0, 0, 0);
        }
        if (win < 7) write_tile((win + 1) & 1, (win + 1) & 1);
        asm volatile("s_waitcnt lgkmcnt(0)" ::: "memory");
        __builtin_amdgcn_s_barrier();
        __builtin_amdgcn_sched_barrier(0);
    }

    // x2 reduce (exact fp32 over raw x)
#pragma unroll
    for (int i = 0; i < 4; ++i) x2_lds[srow][q * 4 + i] = x2p[i];
    __syncthreads();
    if (tid < 64) {
        float ss = 0.f;
#pragma unroll
        for (int j = 0; j < 16; ++j) ss += x2_lds[j][tid];
        x2f[tid] = ss;
    }
    __syncthreads();

    unsigned short* Ab = Aout + (size_t)b * NN * KK;
    float pA0 = 0.f, pA1 = 0.f;
#pragma unroll
    for (int r = 0; r < 4; ++r) {
        int tloc = w * 16 + g * 4 + r;
        float x2r = x2f[tloc];
        float d0v = s2k0 * (x2r - 2.f * acc0[r] + c2k0);
        float d1v = s2k1 * (x2r - 2.f * acc1[r] + c2k1);
        float m = fmaxf(d0v, d1v);
        m = fmaxf(m, __shfl_xor(m, 1));
        m = fmaxf(m, __shfl_xor(m, 2));
        m = fmaxf(m, __shfl_xor(m, 4));
        m = fmaxf(m, __shfl_xor(m, 8));
        float p0 = __expf(d0v - m), p1 = __expf(d1v - m);
        float ss = p0 + p1;
        ss += __shfl_xor(ss, 1);
        ss += __shfl_xor(ss, 2);
        ss += __shfl_xor(ss, 4);
        ss += __shfl_xor(ss, 8);
        float inv = 1.0f / ss;
        float a0 = p0 * inv, a1 = p1 * inv;
        int n = tok_base + tloc;
        unsigned short* pa = Ab + ((size_t)(n >> 3) << 8) + (n & 7);   // [n/8][k=32][n%8]
        pa[c * 8] = f2bf(a0);
        pa[(c + 16) * 8] = f2bf(a1);
        pA0 += a0;
        pA1 += a1;
    }
    pA0 += __shfl_xor(pA0, 16); pA0 += __shfl_xor(pA0, 32);
    pA1 += __shfl_xor(pA1, 16); pA1 += __shfl_xor(pA1, 32);
    if (lane < 16) {
        sA_lds[w][c] = pA0;
        sA_lds[w][c + 16] = pA1;
    }
    __syncthreads();
    if (tid < 32) {
        float ss = sA_lds[0][tid] + sA_lds[1][tid] + sA_lds[2][tid] + sA_lds[3][tid];
        sAp[(b * 64 + chunk) * KK + tid] = ss;
    }
}

// ---------------- pass B: e-partials per (b, 512-tok chunk, 128-d slice) ----------------
// 512 threads (8 waves), no LDS/barriers/atomics; fp32 x, 1 d-row per lane.
__global__ __launch_bounds__(512) void k_agg(const float* __restrict__ x,
                                             const unsigned short* __restrict__ Ain,
                                             float* __restrict__ part) {
    int tid = threadIdx.x;
    int lane = tid & 63;
    int w = tid >> 6;
    int g = lane >> 4, c = lane & 15;
    int bid = blockIdx.x;
    int b = bid >> 5;
    int nc = (bid >> 2) & 7;
    int dh = bid & 3;

    int dr = dh * 128 + w * 16 + c;                       // this lane's d row
    const float* xr = x + ((size_t)b * DD + dr) * NN;
    const unsigned short* Ab = Ain + (size_t)b * NN * KK;

    f32x4 acc0 = {}, acc1 = {};
#pragma unroll 8
    for (int ns = 0; ns < 16; ++ns) {
        int n0 = nc * 512 + ns * 32 + g * 8;
        const unsigned short* pa = Ab + ((size_t)(n0 >> 3) << 8);
        short8 a0 = *reinterpret_cast<const short8*>(pa + c * 8);          // k = c
        short8 a1 = *reinterpret_cast<const short8*>(pa + c * 8 + 128);    // k = c+16
        float4 v0 = *reinterpret_cast<const float4*>(xr + n0);
        float4 v1 = *reinterpret_cast<const float4*>(xr + n0 + 4);
        uint4 pk = make_uint4(pk2(v0.x, v0.y), pk2(v0.z, v0.w),
                              pk2(v1.x, v1.y), pk2(v1.z, v1.w));
        short8 xf = __builtin_bit_cast(short8, pk);
        acc0 = __builtin_amdgcn_mfma_f32_16x16x32_bf16(a0, xf, acc0, 0, 0, 0);
        acc1 = __builtin_amdgcn_mfma_f32_16x16x32_bf16(a1, xf, acc1, 0, 0, 0);
    }
    float* pp = part + (size_t)(b * 8 + nc) * KK * DD;
#pragma unroll
    for (int r = 0; r < 4; ++r) {
        pp[(g * 4 + r) * DD + dr] = acc0[r];
        pp[(16 + g * 4 + r) * DD + dr] = acc1[r];
    }
}

// ---------------- reduce: out = sum_{8 chunks} part - sA*codes ----------------
__global__ __launch_bounds__(256) void k_red(const float* __restrict__ part,
                                             const float* __restrict__ sAp,
                                             const float* __restrict__ codes,
                                             float* __restrict__ out) {
    int bid = blockIdx.x;        // b*32 + k
    int b = bid >> 5, k = bid & 31;
    int tid = threadIdx.x;
    int d = tid * 2;
    float sA = 0.f;
    for (int cc = 0; cc < 64; ++cc) sA += sAp[(b * 64 + cc) * KK + k];   // uniform -> s_loads
    const float* pb = part + (size_t)b * 8 * KK * DD + k * DD + d;
    float s0 = 0.f, s1 = 0.f;
#pragma unroll
    for (int cc = 0; cc < 8; ++cc) {
        float2 v = *reinterpret_cast<const float2*>(pb + (size_t)cc * KK * DD);
        s0 += v.x; s1 += v.y;
    }
    float2 cd = *reinterpret_cast<const float2*>(codes + k * DD + d);
    float2 o;
    o.x = s0 - sA * cd.x;
    o.y = s1 - sA * cd.y;
    *reinterpret_cast<float2*>(out + ((size_t)b * KK + k) * DD + d) = o;
}

extern "C" void kernel_launch(void* const* d_in, const int* in_sizes, int n_in,
                              void* d_out, int out_size, void* d_ws, size_t ws_size,
                              hipStream_t stream) {
    const float* x = (const float*)d_in[0];
    const float* codes = (const float*)d_in[1];
    const float* scale = (const float*)d_in[2];
    float* out = (float*)d_out;
    float* ws = (float*)d_ws;

    float* sAp = ws;                                          // 16*64*32 = 32768 f
    float* c2w = ws + 32768;                                  // 32
    float* s2w = ws + 32800;                                  // 32
    unsigned short* codesP = (unsigned short*)(ws + 32832);   // 32 KB permuted bf16
    unsigned short* Abuf = (unsigned short*)(ws + 41024);     // B*N*K bf16 = 4 MB
    float* part = ws + 41024 + 1048576;                       // 16*8*32*512 f = 8.4 MB

    k_prep<<<1, 256, 0, stream>>>(codes, scale, c2w, s2w, codesP);
    // MEASUREMENT: k_assign launched TWICE (idempotent, deterministic).
    // dur_us - 62.56 == cost of one k_assign dispatch (L3-warm lower bound).
    k_assign<<<BB * 64, 256, 0, stream>>>(x, codesP, c2w, s2w, Abuf, sAp);
    k_assign<<<BB * 64, 256, 0, stream>>>(x, codesP, c2w, s2w, Abuf, sAp);
    k_agg<<<BB * 8 * 4, 512, 0, stream>>>(x, Abuf, part);
    k_red<<<BB * KK, 256, 0, stream>>>(part, sAp, codes, out);
}

// Round 11
// 66.653 us; speedup vs baseline: 1.2975x; 1.2975x over previous
//
#include <hip/hip_runtime.h>
#include <hip/hip_bf16.h>

#define KK 32
#define DD 512
#define BB 16
#define NN 4096

typedef __attribute__((ext_vector_type(8))) short short8;
typedef __attribute__((ext_vector_type(4))) float f32x4;

__device__ __forceinline__ unsigned short f2bf(float f) {
    unsigned u = __builtin_bit_cast(unsigned, f);
    u += 0x7fffu + ((u >> 16) & 1u);   // RNE bf16
    return (unsigned short)(u >> 16);
}
// packed bf16 pair (RNE): low = a, high = b
__device__ __forceinline__ unsigned pk2(float a, float b) {
    return (unsigned)f2bf(a) | ((unsigned)f2bf(b) << 16);
}

// ---------------- kernel 0: c2[k], s2[k], codes -> permuted MFMA-frag layout ----------------
// codesP[it][kt] is a 1KB region: lane(g*16+c) holds codes[kt*16+c][it*32+g*8 .. +7] bf16.
__global__ __launch_bounds__(256) void k_prep(const float* __restrict__ codes,
                                              const float* __restrict__ scale,
                                              float* __restrict__ c2w,
                                              float* __restrict__ s2w,
                                              unsigned short* __restrict__ codesP) {
    __shared__ float red[KK][8];
    int tid = threadIdx.x;
    int k = tid >> 3, pt = tid & 7;
    int kt = k >> 4, cc = k & 15;
    const float4* p = reinterpret_cast<const float4*>(codes + k * DD + pt * 64);
    float s = 0.f;
#pragma unroll
    for (int i = 0; i < 16; ++i) {
        float4 v = p[i];
        s += v.x * v.x + v.y * v.y + v.z * v.z + v.w * v.w;
        int d0 = pt * 64 + i * 4;
        int it = d0 >> 5, g = (d0 >> 3) & 3;
        uint2 pk = make_uint2(pk2(v.x, v.y), pk2(v.z, v.w));
        ushort4 h = __builtin_bit_cast(ushort4, pk);
        int idx = ((it * 2 + kt) << 9) + (g * 16 + cc) * 8 + (d0 & 7);
        *reinterpret_cast<ushort4*>(codesP + idx) = h;
    }
    red[k][pt] = s;
    __syncthreads();
    if (tid < KK) {
        float c2 = 0.f;
#pragma unroll
        for (int j = 0; j < 8; ++j) c2 += red[tid][j];
        c2w[tid] = c2;
        float sc = scale[tid];
        s2w[tid] = sc * sc;
    }
}

// ---------------- pass A: softmax assignments (deep-pipelined staging) ----------------
// 256 thr (4 waves), 64 tokens/block, grid = 1024. 8 windows of 64 d-rows.
// Hot-loop barriers wait lgkmcnt only -> global prefetches stay in flight across barriers.
__global__ __launch_bounds__(256) void k_assign(const float* __restrict__ x,
                                                const unsigned short* __restrict__ codesP,
                                                const float* __restrict__ c2w,
                                                const float* __restrict__ s2w,
                                                unsigned short* __restrict__ Aout,
                                                float* __restrict__ sAp) {
    __shared__ unsigned short xt[2][64 * 64];   // 2 x 8 KB, swizzled [d64][tok64]
    __shared__ float x2_lds[16][64];
    __shared__ float x2f[64];
    __shared__ float sA_lds[4][32];

    int tid = threadIdx.x;
    int lane = tid & 63;
    int w = tid >> 6;          // wave -> 16 tokens
    int g = lane >> 4, c = lane & 15;
    int bid = blockIdx.x;
    int b = bid >> 6;
    int chunk = bid & 63;
    int tok_base = chunk << 6;

    int srow = tid >> 4;       // 0..15 ; rows srow*4 + i (i 0..3) per window
    int q = tid & 15;          // float4 token-column
    const float* xb = x + (size_t)b * DD * NN + tok_base + q * 4;

    float s2k0 = s2w[c], s2k1 = s2w[c + 16];
    float c2k0 = c2w[c], c2k1 = c2w[c + 16];

    f32x4 acc0 = {}, acc1 = {};
    float x2p[4] = {0.f, 0.f, 0.f, 0.f};
    float4 ld[2][4];

    auto issue = [&](int win, int slot) {
#pragma unroll
        for (int i = 0; i < 4; ++i)
            ld[slot][i] = *reinterpret_cast<const float4*>(
                xb + (size_t)(win * 64 + srow * 4 + i) * NN);
    };
    auto write_tile = [&](int buf, int slot) {
        char* bp = reinterpret_cast<char*>(&xt[buf][0]);
#pragma unroll
        for (int i = 0; i < 4; ++i) {
            float4 v = ld[slot][i];
            x2p[0] += v.x * v.x;
            x2p[1] += v.y * v.y;
            x2p[2] += v.z * v.z;
            x2p[3] += v.w * v.w;
            uint2 pk = make_uint2(pk2(v.x, v.y), pk2(v.z, v.w));
            ushort4 h = __builtin_bit_cast(ushort4, pk);
            int rl = srow * 4 + i;
            int byte = ((rl << 7) + (q << 3)) ^ (((rl >> 3) & 3) << 5);
            *reinterpret_cast<ushort4*>(bp + byte) = h;
        }
    };

    issue(0, 0);
    issue(1, 1);
    write_tile(0, 0);
    asm volatile("s_waitcnt lgkmcnt(0)" ::: "memory");
    __builtin_amdgcn_s_barrier();
    __builtin_amdgcn_sched_barrier(0);

#pragma unroll
    for (int win = 0; win < 8; ++win) {
        if (win <= 5) issue(win + 2, win & 1);
        const char* bp = reinterpret_cast<const char*>(&xt[win & 1][0]);
#pragma unroll
        for (int ksl = 0; ksl < 2; ++ksl) {
            int ks = win * 2 + ksl;
            short8 af;
#pragma unroll
            for (int j = 0; j < 8; ++j) {
                int rl = ksl * 32 + g * 8 + j;
                af[j] = *reinterpret_cast<const short*>(
                    bp + ((((rl << 7) + ((w * 16 + c) << 1)) ^ ((g & 3) << 5))));
            }
            // coalesced permuted codes frags (L2-hot): 16B per lane, wave-linear
            short8 b0 = *reinterpret_cast<const short8*>(codesP + ((ks * 2 + 0) << 9) + lane * 8);
            short8 b1 = *reinterpret_cast<const short8*>(codesP + ((ks * 2 + 1) << 9) + lane * 8);
            acc0 = __builtin_amdgcn_mfma_f32_16x16x32_bf16(af, b0, acc0, 0, 0, 0);
            acc1 = __builtin_amdgcn_mfma_f32_16x16x32_bf16(af, b1, acc1, 0, 0, 0);
        }
        if (win < 7) write_tile((win + 1) & 1, (win + 1) & 1);
        asm volatile("s_waitcnt lgkmcnt(0)" ::: "memory");
        __builtin_amdgcn_s_barrier();
        __builtin_amdgcn_sched_barrier(0);
    }

    // x2 reduce (exact fp32 over raw x)
#pragma unroll
    for (int i = 0; i < 4; ++i) x2_lds[srow][q * 4 + i] = x2p[i];
    __syncthreads();
    if (tid < 64) {
        float ss = 0.f;
#pragma unroll
        for (int j = 0; j < 16; ++j) ss += x2_lds[j][tid];
        x2f[tid] = ss;
    }
    __syncthreads();

    unsigned short* Ab = Aout + (size_t)b * NN * KK;
    float pA0 = 0.f, pA1 = 0.f;
#pragma unroll
    for (int r = 0; r < 4; ++r) {
        int tloc = w * 16 + g * 4 + r;
        float x2r = x2f[tloc];
        float d0v = s2k0 * (x2r - 2.f * acc0[r] + c2k0);
        float d1v = s2k1 * (x2r - 2.f * acc1[r] + c2k1);
        float m = fmaxf(d0v, d1v);
        m = fmaxf(m, __shfl_xor(m, 1));
        m = fmaxf(m, __shfl_xor(m, 2));
        m = fmaxf(m, __shfl_xor(m, 4));
        m = fmaxf(m, __shfl_xor(m, 8));
        float p0 = __expf(d0v - m), p1 = __expf(d1v - m);
        float ss = p0 + p1;
        ss += __shfl_xor(ss, 1);
        ss += __shfl_xor(ss, 2);
        ss += __shfl_xor(ss, 4);
        ss += __shfl_xor(ss, 8);
        float inv = 1.0f / ss;
        float a0 = p0 * inv, a1 = p1 * inv;
        int n = tok_base + tloc;
        unsigned short* pa = Ab + ((size_t)(n >> 3) << 8) + (n & 7);   // [n/8][k=32][n%8]
        pa[c * 8] = f2bf(a0);
        pa[(c + 16) * 8] = f2bf(a1);
        pA0 += a0;
        pA1 += a1;
    }
    pA0 += __shfl_xor(pA0, 16); pA0 += __shfl_xor(pA0, 32);
    pA1 += __shfl_xor(pA1, 16); pA1 += __shfl_xor(pA1, 32);
    if (lane < 16) {
        sA_lds[w][c] = pA0;
        sA_lds[w][c + 16] = pA1;
    }
    __syncthreads();
    if (tid < 32) {
        float ss = sA_lds[0][tid] + sA_lds[1][tid] + sA_lds[2][tid] + sA_lds[3][tid];
        sAp[(b * 64 + chunk) * KK + tid] = ss;
    }
}

// ---------------- pass B: e-partials per (b, 256-tok chunk, 64-row d-slice) ----------------
// 256 threads (4 waves), no LDS/barriers/atomics; grid = 16*16*8 = 2048 (8 blocks/CU,
// 32 waves/CU = occupancy cap). Partials indexed by (b, nc) only.
__global__ __launch_bounds__(256) void k_agg(const float* __restrict__ x,
                                             const unsigned short* __restrict__ Ain,
                                             float* __restrict__ part) {
    int tid = threadIdx.x;
    int lane = tid & 63;
    int w = tid >> 6;          // 0..3
    int g = lane >> 4, c = lane & 15;
    int bid = blockIdx.x;
    int b = bid >> 7;
    int nc = (bid >> 3) & 15;  // 16 chunks of 256 tokens
    int dh = bid & 7;          // 8 slices of 64 d-rows

    int dr = dh * 64 + w * 16 + c;                        // this lane's d row
    const float* xr = x + ((size_t)b * DD + dr) * NN;
    const unsigned short* Ab = Ain + (size_t)b * NN * KK;

    f32x4 acc0 = {}, acc1 = {};
#pragma unroll
    for (int ns = 0; ns < 8; ++ns) {
        int n0 = nc * 256 + ns * 32 + g * 8;
        const unsigned short* pa = Ab + ((size_t)(n0 >> 3) << 8);
        short8 a0 = *reinterpret_cast<const short8*>(pa + c * 8);          // k = c
        short8 a1 = *reinterpret_cast<const short8*>(pa + c * 8 + 128);    // k = c+16
        float4 v0 = *reinterpret_cast<const float4*>(xr + n0);
        float4 v1 = *reinterpret_cast<const float4*>(xr + n0 + 4);
        uint4 pk = make_uint4(pk2(v0.x, v0.y), pk2(v0.z, v0.w),
                              pk2(v1.x, v1.y), pk2(v1.z, v1.w));
        short8 xf = __builtin_bit_cast(short8, pk);
        acc0 = __builtin_amdgcn_mfma_f32_16x16x32_bf16(a0, xf, acc0, 0, 0, 0);
        acc1 = __builtin_amdgcn_mfma_f32_16x16x32_bf16(a1, xf, acc1, 0, 0, 0);
    }
    float* pp = part + (size_t)(b * 16 + nc) * KK * DD;
#pragma unroll
    for (int r = 0; r < 4; ++r) {
        pp[(g * 4 + r) * DD + dr] = acc0[r];
        pp[(16 + g * 4 + r) * DD + dr] = acc1[r];
    }
}

// ---------------- reduce: out = sum_{16 chunks} part - sA*codes ----------------
__global__ __launch_bounds__(256) void k_red(const float* __restrict__ part,
                                             const float* __restrict__ sAp,
                                             const float* __restrict__ codes,
                                             float* __restrict__ out) {
    int bid = blockIdx.x;        // b*32 + k
    int b = bid >> 5, k = bid & 31;
    int tid = threadIdx.x;
    int d = tid * 2;
    float sA = 0.f;
    for (int cc = 0; cc < 64; ++cc) sA += sAp[(b * 64 + cc) * KK + k];   // uniform -> s_loads
    const float* pb = part + (size_t)b * 16 * KK * DD + k * DD + d;
    float s0 = 0.f, s1 = 0.f;
#pragma unroll
    for (int cc = 0; cc < 16; ++cc) {
        float2 v = *reinterpret_cast<const float2*>(pb + (size_t)cc * KK * DD);
        s0 += v.x; s1 += v.y;
    }
    float2 cd = *reinterpret_cast<const float2*>(codes + k * DD + d);
    float2 o;
    o.x = s0 - sA * cd.x;
    o.y = s1 - sA * cd.y;
    *reinterpret_cast<float2*>(out + ((size_t)b * KK + k) * DD + d) = o;
}

extern "C" void kernel_launch(void* const* d_in, const int* in_sizes, int n_in,
                              void* d_out, int out_size, void* d_ws, size_t ws_size,
                              hipStream_t stream) {
    const float* x = (const float*)d_in[0];
    const float* codes = (const float*)d_in[1];
    const float* scale = (const float*)d_in[2];
    float* out = (float*)d_out;
    float* ws = (float*)d_ws;

    float* sAp = ws;                                          // 16*64*32 = 32768 f
    float* c2w = ws + 32768;                                  // 32
    float* s2w = ws + 32800;                                  // 32
    unsigned short* codesP = (unsigned short*)(ws + 32832);   // 32 KB permuted bf16
    unsigned short* Abuf = (unsigned short*)(ws + 41024);     // B*N*K bf16 = 4 MB
    float* part = ws + 41024 + 1048576;                       // 16*16*32*512 f = 16.8 MB

    k_prep<<<1, 256, 0, stream>>>(codes, scale, c2w, s2w, codesP);
    k_assign<<<BB * 64, 256, 0, stream>>>(x, codesP, c2w, s2w, Abuf, sAp);
    k_agg<<<BB * 16 * 8, 256, 0, stream>>>(x, Abuf, part);
    k_red<<<BB * KK, 256, 0, stream>>>(part, sAp, codes, out);
}

// Round 12
// 63.052 us; speedup vs baseline: 1.3716x; 1.0571x over previous
//
#include <hip/hip_runtime.h>
#include <hip/hip_bf16.h>

#define KK 32
#define DD 512
#define BB 16
#define NN 4096

typedef __attribute__((ext_vector_type(8))) short short8;
typedef __attribute__((ext_vector_type(4))) float f32x4;

__device__ __forceinline__ unsigned short f2bf(float f) {
    unsigned u = __builtin_bit_cast(unsigned, f);
    u += 0x7fffu + ((u >> 16) & 1u);   // RNE bf16
    return (unsigned short)(u >> 16);
}
// packed bf16 pair (RNE): low = a, high = b
__device__ __forceinline__ unsigned pk2(float a, float b) {
    return (unsigned)f2bf(a) | ((unsigned)f2bf(b) << 16);
}

// ---------------- kernel 0: c2[k], s2[k], codes -> permuted MFMA-frag layout ----------------
// codesP[it][kt] is a 1KB region: lane(g*16+c) holds codes[kt*16+c][it*32+g*8 .. +7] bf16.
__global__ __launch_bounds__(256) void k_prep(const float* __restrict__ codes,
                                              const float* __restrict__ scale,
                                              float* __restrict__ c2w,
                                              float* __restrict__ s2w,
                                              unsigned short* __restrict__ codesP) {
    __shared__ float red[KK][8];
    int tid = threadIdx.x;
    int k = tid >> 3, pt = tid & 7;
    int kt = k >> 4, cc = k & 15;
    const float4* p = reinterpret_cast<const float4*>(codes + k * DD + pt * 64);
    float s = 0.f;
#pragma unroll
    for (int i = 0; i < 16; ++i) {
        float4 v = p[i];
        s += v.x * v.x + v.y * v.y + v.z * v.z + v.w * v.w;
        int d0 = pt * 64 + i * 4;
        int it = d0 >> 5, g = (d0 >> 3) & 3;
        uint2 pk = make_uint2(pk2(v.x, v.y), pk2(v.z, v.w));
        ushort4 h = __builtin_bit_cast(ushort4, pk);
        int idx = ((it * 2 + kt) << 9) + (g * 16 + cc) * 8 + (d0 & 7);
        *reinterpret_cast<ushort4*>(codesP + idx) = h;
    }
    red[k][pt] = s;
    __syncthreads();
    if (tid < KK) {
        float c2 = 0.f;
#pragma unroll
        for (int j = 0; j < 8; ++j) c2 += red[tid][j];
        c2w[tid] = c2;
        float sc = scale[tid];
        s2w[tid] = sc * sc;
    }
}

// ---------------- pass A: softmax assignments (deep-pipelined staging) ----------------
// 256 thr (4 waves), 64 tokens/block, grid = 1024. 8 windows of 64 d-rows.
// Hot-loop barriers wait lgkmcnt only -> global prefetches stay in flight across barriers.
__global__ __launch_bounds__(256) void k_assign(const float* __restrict__ x,
                                                const unsigned short* __restrict__ codesP,
                                                const float* __restrict__ c2w,
                                                const float* __restrict__ s2w,
                                                unsigned short* __restrict__ Aout,
                                                float* __restrict__ sAp) {
    __shared__ unsigned short xt[2][64 * 64];   // 2 x 8 KB, swizzled [d64][tok64]
    __shared__ float x2_lds[16][64];
    __shared__ float x2f[64];
    __shared__ float sA_lds[4][32];

    int tid = threadIdx.x;
    int lane = tid & 63;
    int w = tid >> 6;          // wave -> 16 tokens
    int g = lane >> 4, c = lane & 15;
    int bid = blockIdx.x;
    int b = bid >> 6;
    int chunk = bid & 63;
    int tok_base = chunk << 6;

    int srow = tid >> 4;       // 0..15 ; rows srow*4 + i (i 0..3) per window
    int q = tid & 15;          // float4 token-column
    const float* xb = x + (size_t)b * DD * NN + tok_base + q * 4;

    float s2k0 = s2w[c], s2k1 = s2w[c + 16];
    float c2k0 = c2w[c], c2k1 = c2w[c + 16];

    f32x4 acc0 = {}, acc1 = {};
    float x2p[4] = {0.f, 0.f, 0.f, 0.f};
    float4 ld[2][4];

    auto issue = [&](int win, int slot) {
#pragma unroll
        for (int i = 0; i < 4; ++i)
            ld[slot][i] = *reinterpret_cast<const float4*>(
                xb + (size_t)(win * 64 + srow * 4 + i) * NN);
    };
    auto write_tile = [&](int buf, int slot) {
        char* bp = reinterpret_cast<char*>(&xt[buf][0]);
#pragma unroll
        for (int i = 0; i < 4; ++i) {
            float4 v = ld[slot][i];
            x2p[0] += v.x * v.x;
            x2p[1] += v.y * v.y;
            x2p[2] += v.z * v.z;
            x2p[3] += v.w * v.w;
            uint2 pk = make_uint2(pk2(v.x, v.y), pk2(v.z, v.w));
            ushort4 h = __builtin_bit_cast(ushort4, pk);
            int rl = srow * 4 + i;
            int byte = ((rl << 7) + (q << 3)) ^ (((rl >> 3) & 3) << 5);
            *reinterpret_cast<ushort4*>(bp + byte) = h;
        }
    };

    issue(0, 0);
    issue(1, 1);
    write_tile(0, 0);
    asm volatile("s_waitcnt lgkmcnt(0)" ::: "memory");
    __builtin_amdgcn_s_barrier();
    __builtin_amdgcn_sched_barrier(0);

#pragma unroll
    for (int win = 0; win < 8; ++win) {
        if (win <= 5) issue(win + 2, win & 1);
        const char* bp = reinterpret_cast<const char*>(&xt[win & 1][0]);
#pragma unroll
        for (int ksl = 0; ksl < 2; ++ksl) {
            int ks = win * 2 + ksl;
            short8 af;
#pragma unroll
            for (int j = 0; j < 8; ++j) {
                int rl = ksl * 32 + g * 8 + j;
                af[j] = *reinterpret_cast<const short*>(
                    bp + ((((rl << 7) + ((w * 16 + c) << 1)) ^ ((g & 3) << 5))));
            }
            // coalesced permuted codes frags (L2-hot): 16B per lane, wave-linear
            short8 b0 = *reinterpret_cast<const short8*>(codesP + ((ks * 2 + 0) << 9) + lane * 8);
            short8 b1 = *reinterpret_cast<const short8*>(codesP + ((ks * 2 + 1) << 9) + lane * 8);
            acc0 = __builtin_amdgcn_mfma_f32_16x16x32_bf16(af, b0, acc0, 0, 0, 0);
            acc1 = __builtin_amdgcn_mfma_f32_16x16x32_bf16(af, b1, acc1, 0, 0, 0);
        }
        if (win < 7) write_tile((win + 1) & 1, (win + 1) & 1);
        asm volatile("s_waitcnt lgkmcnt(0)" ::: "memory");
        __builtin_amdgcn_s_barrier();
        __builtin_amdgcn_sched_barrier(0);
    }

    // x2 reduce (exact fp32 over raw x)
#pragma unroll
    for (int i = 0; i < 4; ++i) x2_lds[srow][q * 4 + i] = x2p[i];
    __syncthreads();
    if (tid < 64) {
        float ss = 0.f;
#pragma unroll
        for (int j = 0; j < 16; ++j) ss += x2_lds[j][tid];
        x2f[tid] = ss;
    }
    __syncthreads();

    unsigned short* Ab = Aout + (size_t)b * NN * KK;
    float pA0 = 0.f, pA1 = 0.f;
#pragma unroll
    for (int r = 0; r < 4; ++r) {
        int tloc = w * 16 + g * 4 + r;
        float x2r = x2f[tloc];
        float d0v = s2k0 * (x2r - 2.f * acc0[r] + c2k0);
        float d1v = s2k1 * (x2r - 2.f * acc1[r] + c2k1);
        float m = fmaxf(d0v, d1v);
        m = fmaxf(m, __shfl_xor(m, 1));
        m = fmaxf(m, __shfl_xor(m, 2));
        m = fmaxf(m, __shfl_xor(m, 4));
        m = fmaxf(m, __shfl_xor(m, 8));
        float p0 = __expf(d0v - m), p1 = __expf(d1v - m);
        float ss = p0 + p1;
        ss += __shfl_xor(ss, 1);
        ss += __shfl_xor(ss, 2);
        ss += __shfl_xor(ss, 4);
        ss += __shfl_xor(ss, 8);
        float inv = 1.0f / ss;
        float a0 = p0 * inv, a1 = p1 * inv;
        int n = tok_base + tloc;
        unsigned short* pa = Ab + ((size_t)(n >> 3) << 8) + (n & 7);   // [n/8][k=32][n%8]
        pa[c * 8] = f2bf(a0);
        pa[(c + 16) * 8] = f2bf(a1);
        pA0 += a0;
        pA1 += a1;
    }
    pA0 += __shfl_xor(pA0, 16); pA0 += __shfl_xor(pA0, 32);
    pA1 += __shfl_xor(pA1, 16); pA1 += __shfl_xor(pA1, 32);
    if (lane < 16) {
        sA_lds[w][c] = pA0;
        sA_lds[w][c + 16] = pA1;
    }
    __syncthreads();
    if (tid < 32) {
        float ss = sA_lds[0][tid] + sA_lds[1][tid] + sA_lds[2][tid] + sA_lds[3][tid];
        sAp[(b * 64 + chunk) * KK + tid] = ss;
    }
}

// ---------------- pass B: FINAL e per (b, 16-row d-slice), full-N accumulation ----------------
// 512 threads (8 waves), grid = 16*32 = 512. Wave w sweeps n-chunks {w, w+8, ...}.
// No partials, no k_red: cross-wave LDS reduce + fold -sA*codes, write out directly.
__global__ __launch_bounds__(512) void k_agg(const float* __restrict__ x,
                                             const unsigned short* __restrict__ Ain,
                                             const float* __restrict__ sAp,
                                             const float* __restrict__ codes,
                                             float* __restrict__ out) {
    __shared__ float red[8][32][16];   // 16 KB
    __shared__ float sAl[8][32];       // 1 KB

    int tid = threadIdx.x;
    int lane = tid & 63;
    int w = tid >> 6;          // 0..7
    int g = lane >> 4, c = lane & 15;
    int bid = blockIdx.x;
    int b = bid >> 5;
    int dh = bid & 31;         // 32 slices of 16 d-rows

    int dr = dh * 16 + c;      // this lane's d row
    const float* xr = x + ((size_t)b * DD + dr) * NN;
    const unsigned short* Ab = Ain + (size_t)b * NN * KK;

    f32x4 acc0 = {}, acc1 = {};
#pragma unroll
    for (int j = 0; j < 16; ++j) {
        int n0 = ((j * 8 + w) << 5) + g * 8;   // chunk (j*8+w) of 32 tokens
        const unsigned short* pa = Ab + ((size_t)(n0 >> 3) << 8);
        short8 a0 = *reinterpret_cast<const short8*>(pa + c * 8);          // k = c
        short8 a1 = *reinterpret_cast<const short8*>(pa + c * 8 + 128);    // k = c+16
        float4 v0 = *reinterpret_cast<const float4*>(xr + n0);
        float4 v1 = *reinterpret_cast<const float4*>(xr + n0 + 4);
        uint4 pk = make_uint4(pk2(v0.x, v0.y), pk2(v0.z, v0.w),
                              pk2(v1.x, v1.y), pk2(v1.z, v1.w));
        short8 xf = __builtin_bit_cast(short8, pk);
        acc0 = __builtin_amdgcn_mfma_f32_16x16x32_bf16(a0, xf, acc0, 0, 0, 0);
        acc1 = __builtin_amdgcn_mfma_f32_16x16x32_bf16(a1, xf, acc1, 0, 0, 0);
    }

    // sA[b,k] partials (8 groups x 8 chunks), L2-hot
    if (tid < 256) {
        int k = tid & 31, grp = tid >> 5;
        float s = 0.f;
#pragma unroll
        for (int j2 = 0; j2 < 8; ++j2)
            s += sAp[(size_t)(b * 64 + grp * 8 + j2) * KK + k];
        sAl[grp][k] = s;
    }

    // cross-wave reduce of acc
#pragma unroll
    for (int r = 0; r < 4; ++r) {
        red[w][g * 4 + r][c] = acc0[r];
        red[w][16 + g * 4 + r][c] = acc1[r];
    }
    __syncthreads();

    // one output element per thread: k = tid>>4, d = tid&15
    int k = tid >> 4, d = tid & 15;
    float val = 0.f;
#pragma unroll
    for (int ww = 0; ww < 8; ++ww) val += red[ww][k][d];
    float sk = 0.f;
#pragma unroll
    for (int grp = 0; grp < 8; ++grp) sk += sAl[grp][k];
    int dd = dh * 16 + d;
    out[((size_t)(b * KK + k)) * DD + dd] = val - sk * codes[k * DD + dd];
}

extern "C" void kernel_launch(void* const* d_in, const int* in_sizes, int n_in,
                              void* d_out, int out_size, void* d_ws, size_t ws_size,
                              hipStream_t stream) {
    const float* x = (const float*)d_in[0];
    const float* codes = (const float*)d_in[1];
    const float* scale = (const float*)d_in[2];
    float* out = (float*)d_out;
    float* ws = (float*)d_ws;

    float* sAp = ws;                                          // 16*64*32 = 32768 f
    float* c2w = ws + 32768;                                  // 32
    float* s2w = ws + 32800;                                  // 32
    unsigned short* codesP = (unsigned short*)(ws + 32832);   // 32 KB permuted bf16
    unsigned short* Abuf = (unsigned short*)(ws + 41024);     // B*N*K bf16 = 4 MB

    k_prep<<<1, 256, 0, stream>>>(codes, scale, c2w, s2w, codesP);
    k_assign<<<BB * 64, 256, 0, stream>>>(x, codesP, c2w, s2w, Abuf, sAp);
    k_agg<<<BB * 32, 512, 0, stream>>>(x, Abuf, sAp, codes, out);
}

// Round 13
// 55.068 us; speedup vs baseline: 1.5704x; 1.1450x over previous
//
#include <hip/hip_runtime.h>
#include <hip/hip_bf16.h>

#define KK 32
#define DD 512
#define BB 16
#define NN 4096

typedef __attribute__((ext_vector_type(8))) short short8;
typedef __attribute__((ext_vector_type(4))) float f32x4;

__device__ __forceinline__ unsigned short f2bf(float f) {
    unsigned u = __builtin_bit_cast(unsigned, f);
    u += 0x7fffu + ((u >> 16) & 1u);   // RNE bf16
    return (unsigned short)(u >> 16);
}
// packed bf16 pair (RNE): low = a, high = b
__device__ __forceinline__ unsigned pk2(float a, float b) {
    return (unsigned)f2bf(a) | ((unsigned)f2bf(b) << 16);
}
__device__ __forceinline__ short8 pk8(float4 a, float4 b) {
    uint4 pk = make_uint4(pk2(a.x, a.y), pk2(a.z, a.w), pk2(b.x, b.y), pk2(b.z, b.w));
    return __builtin_bit_cast(short8, pk);
}

// ---------------- kernel 0: c2[k], s2[k], codes -> permuted MFMA-frag layout ----------------
__global__ __launch_bounds__(256) void k_prep(const float* __restrict__ codes,
                                              const float* __restrict__ scale,
                                              float* __restrict__ c2w,
                                              float* __restrict__ s2w,
                                              unsigned short* __restrict__ codesP) {
    __shared__ float red[KK][8];
    int tid = threadIdx.x;
    int k = tid >> 3, pt = tid & 7;
    int kt = k >> 4, cc = k & 15;
    const float4* p = reinterpret_cast<const float4*>(codes + k * DD + pt * 64);
    float s = 0.f;
#pragma unroll
    for (int i = 0; i < 16; ++i) {
        float4 v = p[i];
        s += v.x * v.x + v.y * v.y + v.z * v.z + v.w * v.w;
        int d0 = pt * 64 + i * 4;
        int it = d0 >> 5, g = (d0 >> 3) & 3;
        uint2 pk = make_uint2(pk2(v.x, v.y), pk2(v.z, v.w));
        ushort4 h = __builtin_bit_cast(ushort4, pk);
        int idx = ((it * 2 + kt) << 9) + (g * 16 + cc) * 8 + (d0 & 7);
        *reinterpret_cast<ushort4*>(codesP + idx) = h;
    }
    red[k][pt] = s;
    __syncthreads();
    if (tid < KK) {
        float c2 = 0.f;
#pragma unroll
        for (int j = 0; j < 8; ++j) c2 += red[tid][j];
        c2w[tid] = c2;
        float sc = scale[tid];
        s2w[tid] = sc * sc;
    }
}

// ---------------- pass A: softmax assignments (deep-pipelined staging) ----------------
// unchanged from round 9/12 (measured ~24 µs ≈ 89% of BW floor)
__global__ __launch_bounds__(256) void k_assign(const float* __restrict__ x,
                                                const unsigned short* __restrict__ codesP,
                                                const float* __restrict__ c2w,
                                                const float* __restrict__ s2w,
                                                unsigned short* __restrict__ Aout,
                                                float* __restrict__ sAp) {
    __shared__ unsigned short xt[2][64 * 64];   // 2 x 8 KB, swizzled [d64][tok64]
    __shared__ float x2_lds[16][64];
    __shared__ float x2f[64];
    __shared__ float sA_lds[4][32];

    int tid = threadIdx.x;
    int lane = tid & 63;
    int w = tid >> 6;          // wave -> 16 tokens
    int g = lane >> 4, c = lane & 15;
    int bid = blockIdx.x;
    int b = bid >> 6;
    int chunk = bid & 63;
    int tok_base = chunk << 6;

    int srow = tid >> 4;       // 0..15 ; rows srow*4 + i (i 0..3) per window
    int q = tid & 15;          // float4 token-column
    const float* xb = x + (size_t)b * DD * NN + tok_base + q * 4;

    float s2k0 = s2w[c], s2k1 = s2w[c + 16];
    float c2k0 = c2w[c], c2k1 = c2w[c + 16];

    f32x4 acc0 = {}, acc1 = {};
    float x2p[4] = {0.f, 0.f, 0.f, 0.f};
    float4 ld[2][4];

    auto issue = [&](int win, int slot) {
#pragma unroll
        for (int i = 0; i < 4; ++i)
            ld[slot][i] = *reinterpret_cast<const float4*>(
                xb + (size_t)(win * 64 + srow * 4 + i) * NN);
    };
    auto write_tile = [&](int buf, int slot) {
        char* bp = reinterpret_cast<char*>(&xt[buf][0]);
#pragma unroll
        for (int i = 0; i < 4; ++i) {
            float4 v = ld[slot][i];
            x2p[0] += v.x * v.x;
            x2p[1] += v.y * v.y;
            x2p[2] += v.z * v.z;
            x2p[3] += v.w * v.w;
            uint2 pk = make_uint2(pk2(v.x, v.y), pk2(v.z, v.w));
            ushort4 h = __builtin_bit_cast(ushort4, pk);
            int rl = srow * 4 + i;
            int byte = ((rl << 7) + (q << 3)) ^ (((rl >> 3) & 3) << 5);
            *reinterpret_cast<ushort4*>(bp + byte) = h;
        }
    };

    issue(0, 0);
    issue(1, 1);
    write_tile(0, 0);
    asm volatile("s_waitcnt lgkmcnt(0)" ::: "memory");
    __builtin_amdgcn_s_barrier();
    __builtin_amdgcn_sched_barrier(0);

#pragma unroll
    for (int win = 0; win < 8; ++win) {
        if (win <= 5) issue(win + 2, win & 1);
        const char* bp = reinterpret_cast<const char*>(&xt[win & 1][0]);
#pragma unroll
        for (int ksl = 0; ksl < 2; ++ksl) {
            int ks = win * 2 + ksl;
            short8 af;
#pragma unroll
            for (int j = 0; j < 8; ++j) {
                int rl = ksl * 32 + g * 8 + j;
                af[j] = *reinterpret_cast<const short*>(
                    bp + ((((rl << 7) + ((w * 16 + c) << 1)) ^ ((g & 3) << 5))));
            }
            short8 b0 = *reinterpret_cast<const short8*>(codesP + ((ks * 2 + 0) << 9) + lane * 8);
            short8 b1 = *reinterpret_cast<const short8*>(codesP + ((ks * 2 + 1) << 9) + lane * 8);
            acc0 = __builtin_amdgcn_mfma_f32_16x16x32_bf16(af, b0, acc0, 0, 0, 0);
            acc1 = __builtin_amdgcn_mfma_f32_16x16x32_bf16(af, b1, acc1, 0, 0, 0);
        }
        if (win < 7) write_tile((win + 1) & 1, (win + 1) & 1);
        asm volatile("s_waitcnt lgkmcnt(0)" ::: "memory");
        __builtin_amdgcn_s_barrier();
        __builtin_amdgcn_sched_barrier(0);
    }

    // x2 reduce (exact fp32 over raw x)
#pragma unroll
    for (int i = 0; i < 4; ++i) x2_lds[srow][q * 4 + i] = x2p[i];
    __syncthreads();
    if (tid < 64) {
        float ss = 0.f;
#pragma unroll
        for (int j = 0; j < 16; ++j) ss += x2_lds[j][tid];
        x2f[tid] = ss;
    }
    __syncthreads();

    unsigned short* Ab = Aout + (size_t)b * NN * KK;
    float pA0 = 0.f, pA1 = 0.f;
#pragma unroll
    for (int r = 0; r < 4; ++r) {
        int tloc = w * 16 + g * 4 + r;
        float x2r = x2f[tloc];
        float d0v = s2k0 * (x2r - 2.f * acc0[r] + c2k0);
        float d1v = s2k1 * (x2r - 2.f * acc1[r] + c2k1);
        float m = fmaxf(d0v, d1v);
        m = fmaxf(m, __shfl_xor(m, 1));
        m = fmaxf(m, __shfl_xor(m, 2));
        m = fmaxf(m, __shfl_xor(m, 4));
        m = fmaxf(m, __shfl_xor(m, 8));
        float p0 = __expf(d0v - m), p1 = __expf(d1v - m);
        float ss = p0 + p1;
        ss += __shfl_xor(ss, 1);
        ss += __shfl_xor(ss, 2);
        ss += __shfl_xor(ss, 4);
        ss += __shfl_xor(ss, 8);
        float inv = 1.0f / ss;
        float a0 = p0 * inv, a1 = p1 * inv;
        int n = tok_base + tloc;
        unsigned short* pa = Ab + ((size_t)(n >> 3) << 8) + (n & 7);   // [n/8][k=32][n%8]
        pa[c * 8] = f2bf(a0);
        pa[(c + 16) * 8] = f2bf(a1);
        pA0 += a0;
        pA1 += a1;
    }
    pA0 += __shfl_xor(pA0, 16); pA0 += __shfl_xor(pA0, 32);
    pA1 += __shfl_xor(pA1, 16); pA1 += __shfl_xor(pA1, 32);
    if (lane < 16) {
        sA_lds[w][c] = pA0;
        sA_lds[w][c + 16] = pA1;
    }
    __syncthreads();
    if (tid < 32) {
        float ss = sA_lds[0][tid] + sA_lds[1][tid] + sA_lds[2][tid] + sA_lds[3][tid];
        sAp[(b * 64 + chunk) * KK + tid] = ss;
    }
}

// ---------------- pass B: FINAL e per (b, 32-row d-slice), full-N, A read once/block ----------
// 1024 threads (16 waves, 1 block/CU), grid = 16*16 = 256. Wave w sweeps n-sixteenths.
// Each lane covers 2 d-rows -> each A-fragment feeds 4 MFMAs (A traffic halved vs r12).
// XCD-cluster swizzle: each XCD owns 2 whole batches -> A[b]/x[b] L2-local.
__global__ __launch_bounds__(1024) void k_agg(const float* __restrict__ x,
                                              const unsigned short* __restrict__ Ain,
                                              const float* __restrict__ sAp,
                                              const float* __restrict__ codes,
                                              float* __restrict__ out) {
    __shared__ float red[16][32][32];   // 64 KB
    __shared__ float sAl[8][32];        // 1 KB

    int tid = threadIdx.x;
    int lane = tid & 63;
    int w = tid >> 6;          // 0..15 (n-sixteenth)
    int g = lane >> 4, c = lane & 15;
    int bid0 = blockIdx.x;
    int bid = ((bid0 & 7) << 5) + (bid0 >> 3);   // bijective XCD-cluster swizzle (256 = 8*32)
    int b = bid >> 4;
    int dh = bid & 15;         // 16 slices of 32 d-rows

    int dr = dh * 32 + c;      // lane's d rows: dr, dr+16
    const float* xr0 = x + ((size_t)b * DD + dr) * NN;
    const float* xr1 = xr0 + (size_t)16 * NN;
    const unsigned short* Ab = Ain + (size_t)b * NN * KK;

    f32x4 acc[2][2] = {};      // [kt][dt]
#pragma unroll
    for (int j = 0; j < 8; ++j) {
        int n0 = ((j * 16 + w) << 5) + g * 8;    // this wave's 32-token chunk
        const unsigned short* pa = Ab + ((size_t)(n0 >> 3) << 8);
        short8 a0 = *reinterpret_cast<const short8*>(pa + c * 8);          // k = c
        short8 a1 = *reinterpret_cast<const short8*>(pa + c * 8 + 128);    // k = c+16
        float4 u0 = *reinterpret_cast<const float4*>(xr0 + n0);
        float4 u1 = *reinterpret_cast<const float4*>(xr0 + n0 + 4);
        float4 v0 = *reinterpret_cast<const float4*>(xr1 + n0);
        float4 v1 = *reinterpret_cast<const float4*>(xr1 + n0 + 4);
        short8 xf0 = pk8(u0, u1);
        short8 xf1 = pk8(v0, v1);
        acc[0][0] = __builtin_amdgcn_mfma_f32_16x16x32_bf16(a0, xf0, acc[0][0], 0, 0, 0);
        acc[1][0] = __builtin_amdgcn_mfma_f32_16x16x32_bf16(a1, xf0, acc[1][0], 0, 0, 0);
        acc[0][1] = __builtin_amdgcn_mfma_f32_16x16x32_bf16(a0, xf1, acc[0][1], 0, 0, 0);
        acc[1][1] = __builtin_amdgcn_mfma_f32_16x16x32_bf16(a1, xf1, acc[1][1], 0, 0, 0);
    }

    // sA[b,k] (L2-hot)
    if (tid < 256) {
        int k = tid & 31, grp = tid >> 5;
        float s = 0.f;
#pragma unroll
        for (int j2 = 0; j2 < 8; ++j2)
            s += sAp[(size_t)(b * 64 + grp * 8 + j2) * KK + k];
        sAl[grp][k] = s;
    }

    // cross-wave reduce: red[w][k][d]  (k = kt*16+g*4+r, d = dt*16+c)
#pragma unroll
    for (int kt = 0; kt < 2; ++kt)
#pragma unroll
        for (int dt = 0; dt < 2; ++dt)
#pragma unroll
            for (int r = 0; r < 4; ++r)
                red[w][kt * 16 + g * 4 + r][dt * 16 + c] = acc[kt][dt][r];
    __syncthreads();

    // one output element per thread: k = tid>>5, d = tid&31
    int k = tid >> 5, d = tid & 31;
    float val = 0.f;
#pragma unroll
    for (int ww = 0; ww < 16; ++ww) val += red[ww][k][d];
    float sk = 0.f;
#pragma unroll
    for (int grp = 0; grp < 8; ++grp) sk += sAl[grp][k];
    int dd = dh * 32 + d;
    out[((size_t)(b * KK + k)) * DD + dd] = val - sk * codes[k * DD + dd];
}

extern "C" void kernel_launch(void* const* d_in, const int* in_sizes, int n_in,
                              void* d_out, int out_size, void* d_ws, size_t ws_size,
                              hipStream_t stream) {
    const float* x = (const float*)d_in[0];
    const float* codes = (const float*)d_in[1];
    const float* scale = (const float*)d_in[2];
    float* out = (float*)d_out;
    float* ws = (float*)d_ws;

    float* sAp = ws;                                          // 16*64*32 = 32768 f
    float* c2w = ws + 32768;                                  // 32
    float* s2w = ws + 32800;                                  // 32
    unsigned short* codesP = (unsigned short*)(ws + 32832);   // 32 KB permuted bf16
    unsigned short* Abuf = (unsigned short*)(ws + 41024);     // B*N*K bf16 = 4 MB

    k_prep<<<1, 256, 0, stream>>>(codes, scale, c2w, s2w, codesP);
    k_assign<<<BB * 64, 256, 0, stream>>>(x, codesP, c2w, s2w, Abuf, sAp);
    k_agg<<<BB * 16, 1024, 0, stream>>>(x, Abuf, sAp, codes, out);
}

// Round 14
// 54.944 us; speedup vs baseline: 1.5740x; 1.0023x over previous
//
#include <hip/hip_runtime.h>
#include <hip/hip_bf16.h>

#define KK 32
#define DD 512
#define BB 16
#define NN 4096

typedef __attribute__((ext_vector_type(8))) short short8;
typedef __attribute__((ext_vector_type(4))) float f32x4;

__device__ __forceinline__ unsigned short f2bf(float f) {
    unsigned u = __builtin_bit_cast(unsigned, f);
    u += 0x7fffu + ((u >> 16) & 1u);   // RNE bf16
    return (unsigned short)(u >> 16);
}
// packed bf16 pair (RNE): low = a, high = b
__device__ __forceinline__ unsigned pk2(float a, float b) {
    return (unsigned)f2bf(a) | ((unsigned)f2bf(b) << 16);
}

// ---------------- kernel 0: c2[k], s2[k], codes -> permuted MFMA-frag layout ----------------
__global__ __launch_bounds__(256) void k_prep(const float* __restrict__ codes,
                                              const float* __restrict__ scale,
                                              float* __restrict__ c2w,
                                              float* __restrict__ s2w,
                                              unsigned short* __restrict__ codesP) {
    __shared__ float red[KK][8];
    int tid = threadIdx.x;
    int k = tid >> 3, pt = tid & 7;
    int kt = k >> 4, cc = k & 15;
    const float4* p = reinterpret_cast<const float4*>(codes + k * DD + pt * 64);
    float s = 0.f;
#pragma unroll
    for (int i = 0; i < 16; ++i) {
        float4 v = p[i];
        s += v.x * v.x + v.y * v.y + v.z * v.z + v.w * v.w;
        int d0 = pt * 64 + i * 4;
        int it = d0 >> 5, g = (d0 >> 3) & 3;
        uint2 pk = make_uint2(pk2(v.x, v.y), pk2(v.z, v.w));
        ushort4 h = __builtin_bit_cast(ushort4, pk);
        int idx = ((it * 2 + kt) << 9) + (g * 16 + cc) * 8 + (d0 & 7);
        *reinterpret_cast<ushort4*>(codesP + idx) = h;
    }
    red[k][pt] = s;
    __syncthreads();
    if (tid < KK) {
        float c2 = 0.f;
#pragma unroll
        for (int j = 0; j < 8; ++j) c2 += red[tid][j];
        c2w[tid] = c2;
        float sc = scale[tid];
        s2w[tid] = sc * sc;
    }
}

// ---------------- pass A: softmax assignments + bf16 x-relay ----------------
// r9 pipelined structure + one extra posted ushort4 store per staged quad (x-relay).
__global__ __launch_bounds__(256) void k_assign(const float* __restrict__ x,
                                                const unsigned short* __restrict__ codesP,
                                                const float* __restrict__ c2w,
                                                const float* __restrict__ s2w,
                                                unsigned short* __restrict__ Aout,
                                                unsigned short* __restrict__ xrel,
                                                float* __restrict__ sAp) {
    __shared__ unsigned short xt[2][64 * 64];   // 2 x 8 KB, swizzled [d64][tok64]
    __shared__ float x2_lds[16][64];
    __shared__ float x2f[64];
    __shared__ float sA_lds[4][32];

    int tid = threadIdx.x;
    int lane = tid & 63;
    int w = tid >> 6;          // wave -> 16 tokens
    int g = lane >> 4, c = lane & 15;
    int bid = blockIdx.x;
    int b = bid >> 6;
    int chunk = bid & 63;
    int tok_base = chunk << 6;

    int srow = tid >> 4;       // 0..15 ; rows srow*4 + i (i 0..3) per window
    int q = tid & 15;          // float4 token-column
    const float* xb = x + (size_t)b * DD * NN + tok_base + q * 4;
    unsigned short* xrb = xrel + (size_t)b * DD * NN + tok_base + q * 4;

    float s2k0 = s2w[c], s2k1 = s2w[c + 16];
    float c2k0 = c2w[c], c2k1 = c2w[c + 16];

    f32x4 acc0 = {}, acc1 = {};
    float x2p[4] = {0.f, 0.f, 0.f, 0.f};
    float4 ld[2][4];

    auto issue = [&](int win, int slot) {
#pragma unroll
        for (int i = 0; i < 4; ++i)
            ld[slot][i] = *reinterpret_cast<const float4*>(
                xb + (size_t)(win * 64 + srow * 4 + i) * NN);
    };
    auto write_tile = [&](int buf, int slot, int win) {
        char* bp = reinterpret_cast<char*>(&xt[buf][0]);
#pragma unroll
        for (int i = 0; i < 4; ++i) {
            float4 v = ld[slot][i];
            x2p[0] += v.x * v.x;
            x2p[1] += v.y * v.y;
            x2p[2] += v.z * v.z;
            x2p[3] += v.w * v.w;
            uint2 pk = make_uint2(pk2(v.x, v.y), pk2(v.z, v.w));
            ushort4 h = __builtin_bit_cast(ushort4, pk);
            int rl = srow * 4 + i;
            int byte = ((rl << 7) + (q << 3)) ^ (((rl >> 3) & 3) << 5);
            *reinterpret_cast<ushort4*>(bp + byte) = h;
            // bf16 relay (linear [d][n]) for pass B — posted store, L3-resident
            *reinterpret_cast<ushort4*>(xrb + (size_t)(win * 64 + rl) * NN) = h;
        }
    };

    issue(0, 0);
    issue(1, 1);
    write_tile(0, 0, 0);
    asm volatile("s_waitcnt lgkmcnt(0)" ::: "memory");
    __builtin_amdgcn_s_barrier();
    __builtin_amdgcn_sched_barrier(0);

#pragma unroll
    for (int win = 0; win < 8; ++win) {
        if (win <= 5) issue(win + 2, win & 1);
        const char* bp = reinterpret_cast<const char*>(&xt[win & 1][0]);
#pragma unroll
        for (int ksl = 0; ksl < 2; ++ksl) {
            int ks = win * 2 + ksl;
            short8 af;
#pragma unroll
            for (int j = 0; j < 8; ++j) {
                int rl = ksl * 32 + g * 8 + j;
                af[j] = *reinterpret_cast<const short*>(
                    bp + ((((rl << 7) + ((w * 16 + c) << 1)) ^ ((g & 3) << 5))));
            }
            short8 b0 = *reinterpret_cast<const short8*>(codesP + ((ks * 2 + 0) << 9) + lane * 8);
            short8 b1 = *reinterpret_cast<const short8*>(codesP + ((ks * 2 + 1) << 9) + lane * 8);
            acc0 = __builtin_amdgcn_mfma_f32_16x16x32_bf16(af, b0, acc0, 0, 0, 0);
            acc1 = __builtin_amdgcn_mfma_f32_16x16x32_bf16(af, b1, acc1, 0, 0, 0);
        }
        if (win < 7) write_tile((win + 1) & 1, (win + 1) & 1, win + 1);
        asm volatile("s_waitcnt lgkmcnt(0)" ::: "memory");
        __builtin_amdgcn_s_barrier();
        __builtin_amdgcn_sched_barrier(0);
    }

    // x2 reduce (exact fp32 over raw x)
#pragma unroll
    for (int i = 0; i < 4; ++i) x2_lds[srow][q * 4 + i] = x2p[i];
    __syncthreads();
    if (tid < 64) {
        float ss = 0.f;
#pragma unroll
        for (int j = 0; j < 16; ++j) ss += x2_lds[j][tid];
        x2f[tid] = ss;
    }
    __syncthreads();

    unsigned short* Ab = Aout + (size_t)b * NN * KK;
    float pA0 = 0.f, pA1 = 0.f;
#pragma unroll
    for (int r = 0; r < 4; ++r) {
        int tloc = w * 16 + g * 4 + r;
        float x2r = x2f[tloc];
        float d0v = s2k0 * (x2r - 2.f * acc0[r] + c2k0);
        float d1v = s2k1 * (x2r - 2.f * acc1[r] + c2k1);
        float m = fmaxf(d0v, d1v);
        m = fmaxf(m, __shfl_xor(m, 1));
        m = fmaxf(m, __shfl_xor(m, 2));
        m = fmaxf(m, __shfl_xor(m, 4));
        m = fmaxf(m, __shfl_xor(m, 8));
        float p0 = __expf(d0v - m), p1 = __expf(d1v - m);
        float ss = p0 + p1;
        ss += __shfl_xor(ss, 1);
        ss += __shfl_xor(ss, 2);
        ss += __shfl_xor(ss, 4);
        ss += __shfl_xor(ss, 8);
        float inv = 1.0f / ss;
        float a0 = p0 * inv, a1 = p1 * inv;
        int n = tok_base + tloc;
        unsigned short* pa = Ab + ((size_t)(n >> 3) << 8) + (n & 7);   // [n/8][k=32][n%8]
        pa[c * 8] = f2bf(a0);
        pa[(c + 16) * 8] = f2bf(a1);
        pA0 += a0;
        pA1 += a1;
    }
    pA0 += __shfl_xor(pA0, 16); pA0 += __shfl_xor(pA0, 32);
    pA1 += __shfl_xor(pA1, 16); pA1 += __shfl_xor(pA1, 32);
    if (lane < 16) {
        sA_lds[w][c] = pA0;
        sA_lds[w][c + 16] = pA1;
    }
    __syncthreads();
    if (tid < 32) {
        float ss = sA_lds[0][tid] + sA_lds[1][tid] + sA_lds[2][tid] + sA_lds[3][tid];
        sAp[(b * 64 + chunk) * KK + tid] = ss;
    }
}

// ---------------- pass B: FINAL e per (b, 32-row d-slice), bf16 relay input ----------------
// r13 structure; x read as bf16 relay (half traffic, L3-hot, no pack VALU in hot loop).
__global__ __launch_bounds__(1024) void k_agg(const unsigned short* __restrict__ xrel,
                                              const unsigned short* __restrict__ Ain,
                                              const float* __restrict__ sAp,
                                              const float* __restrict__ codes,
                                              float* __restrict__ out) {
    __shared__ float red[16][32][32];   // 64 KB
    __shared__ float sAl[8][32];        // 1 KB

    int tid = threadIdx.x;
    int lane = tid & 63;
    int w = tid >> 6;          // 0..15 (n-sixteenth)
    int g = lane >> 4, c = lane & 15;
    int bid0 = blockIdx.x;
    int bid = ((bid0 & 7) << 5) + (bid0 >> 3);   // bijective XCD-cluster swizzle (256 = 8*32)
    int b = bid >> 4;
    int dh = bid & 15;         // 16 slices of 32 d-rows

    int dr = dh * 32 + c;      // lane's d rows: dr, dr+16
    const unsigned short* xr0 = xrel + ((size_t)b * DD + dr) * NN;
    const unsigned short* xr1 = xr0 + (size_t)16 * NN;
    const unsigned short* Ab = Ain + (size_t)b * NN * KK;

    f32x4 acc[2][2] = {};      // [kt][dt]
#pragma unroll
    for (int j = 0; j < 8; ++j) {
        int n0 = ((j * 16 + w) << 5) + g * 8;    // this wave's 32-token chunk
        const unsigned short* pa = Ab + ((size_t)(n0 >> 3) << 8);
        short8 a0 = *reinterpret_cast<const short8*>(pa + c * 8);          // k = c
        short8 a1 = *reinterpret_cast<const short8*>(pa + c * 8 + 128);    // k = c+16
        short8 xf0 = *reinterpret_cast<const short8*>(xr0 + n0);
        short8 xf1 = *reinterpret_cast<const short8*>(xr1 + n0);
        acc[0][0] = __builtin_amdgcn_mfma_f32_16x16x32_bf16(a0, xf0, acc[0][0], 0, 0, 0);
        acc[1][0] = __builtin_amdgcn_mfma_f32_16x16x32_bf16(a1, xf0, acc[1][0], 0, 0, 0);
        acc[0][1] = __builtin_amdgcn_mfma_f32_16x16x32_bf16(a0, xf1, acc[0][1], 0, 0, 0);
        acc[1][1] = __builtin_amdgcn_mfma_f32_16x16x32_bf16(a1, xf1, acc[1][1], 0, 0, 0);
    }

    // sA[b,k] (L2-hot)
    if (tid < 256) {
        int k = tid & 31, grp = tid >> 5;
        float s = 0.f;
#pragma unroll
        for (int j2 = 0; j2 < 8; ++j2)
            s += sAp[(size_t)(b * 64 + grp * 8 + j2) * KK + k];
        sAl[grp][k] = s;
    }

    // cross-wave reduce: red[w][k][d]  (k = kt*16+g*4+r, d = dt*16+c)
#pragma unroll
    for (int kt = 0; kt < 2; ++kt)
#pragma unroll
        for (int dt = 0; dt < 2; ++dt)
#pragma unroll
            for (int r = 0; r < 4; ++r)
                red[w][kt * 16 + g * 4 + r][dt * 16 + c] = acc[kt][dt][r];
    __syncthreads();

    // one output element per thread: k = tid>>5, d = tid&31
    int k = tid >> 5, d = tid & 31;
    float val = 0.f;
#pragma unroll
    for (int ww = 0; ww < 16; ++ww) val += red[ww][k][d];
    float sk = 0.f;
#pragma unroll
    for (int grp = 0; grp < 8; ++grp) sk += sAl[grp][k];
    int dd = dh * 32 + d;
    out[((size_t)(b * KK + k)) * DD + dd] = val - sk * codes[k * DD + dd];
}

extern "C" void kernel_launch(void* const* d_in, const int* in_sizes, int n_in,
                              void* d_out, int out_size, void* d_ws, size_t ws_size,
                              hipStream_t stream) {
    const float* x = (const float*)d_in[0];
    const float* codes = (const float*)d_in[1];
    const float* scale = (const float*)d_in[2];
    float* out = (float*)d_out;
    float* ws = (float*)d_ws;

    float* sAp = ws;                                          // 16*64*32 = 32768 f
    float* c2w = ws + 32768;                                  // 32
    float* s2w = ws + 32800;                                  // 32
    unsigned short* codesP = (unsigned short*)(ws + 32832);   // 32 KB permuted bf16
    unsigned short* Abuf = (unsigned short*)(ws + 41024);     // B*N*K bf16 = 4 MB
    unsigned short* xrel = (unsigned short*)(ws + 41024 + 1048576);  // B*D*N bf16 = 64 MB

    k_prep<<<1, 256, 0, stream>>>(codes, scale, c2w, s2w, codesP);
    k_assign<<<BB * 64, 256, 0, stream>>>(x, codesP, c2w, s2w, Abuf, xrel, sAp);
    k_agg<<<BB * 16, 1024, 0, stream>>>(xrel, Abuf, sAp, codes, out);
}